// Round 13
// baseline (444.053 us; speedup 1.0000x reference)
//
#include <hip/hip_runtime.h>
#include <hip/hip_bf16.h>
#include <math.h>

#define LDIM 4096
#define PDIM 4098   // 1-elem reflect pad each side
#define EPSF 1e-9f

using f32x4  = __attribute__((ext_vector_type(4))) float;
using f32x16 = __attribute__((ext_vector_type(16))) float;
using short8 = __attribute__((ext_vector_type(8))) short;

#define AS1 __attribute__((address_space(1)))
#define AS3 __attribute__((address_space(3)))

__device__ __forceinline__ void gload_lds16(const void* g, void* l) {
    __builtin_amdgcn_global_load_lds((const AS1 unsigned int*)g,
                                     (AS3 unsigned int*)l, 16, 0, 0);
}

__device__ __forceinline__ float bf2f(unsigned short u) {
    unsigned int b = ((unsigned int)u) << 16;
    return __builtin_bit_cast(float, b);
}

// ---------------- sp = (s*mask).sum(-1)/len  ----------------
__global__ void sp_kernel(const float* __restrict__ s, const int* __restrict__ lengths,
                          float* __restrict__ sp) {
    int b = blockIdx.x >> 7;
    int d = blockIdx.x & 127;
    int len = lengths[b];
    const float* row = s + ((size_t)(b * 128 + d)) * LDIM;
    float acc = 0.f;
    int len4 = len & ~3;
    for (int l = threadIdx.x * 4; l < len4; l += 1024) {
        f32x4 v = *(const f32x4*)(row + l);
        acc += v[0] + v[1] + v[2] + v[3];
    }
    for (int l = len4 + threadIdx.x; l < len; l += 256) acc += row[l];
    for (int off = 32; off; off >>= 1) acc += __shfl_down(acc, off, 64);
    __shared__ float red[4];
    if ((threadIdx.x & 63) == 0) red[threadIdx.x >> 6] = acc;
    __syncthreads();
    if (threadIdx.x == 0)
        sp[b * 128 + d] = (red[0] + red[1] + red[2] + red[3]) / (float)len;
}

// ---------------- h1 = sp@fc1^T+b1, h2 = sp@fc2^T+b2 ----------------
__global__ void fc_kernel(const float* __restrict__ sp,
                          const float* __restrict__ w1, const float* __restrict__ b1,
                          const float* __restrict__ w2, const float* __restrict__ b2,
                          float* __restrict__ h1, float* __restrict__ h2) {
    int idx = blockIdx.x * 256 + threadIdx.x;   // 16 * 1536
    int b = idx / 1536, j = idx % 1536;
    const float* spb = sp + b * 128;
    if (j < 512) {
        const float* wr = w1 + (size_t)j * 128;
        float acc = b1[j];
        for (int d = 0; d < 128; ++d) acc = fmaf(spb[d], wr[d], acc);
        h1[b * 512 + j] = acc;
    } else {
        int j2 = j - 512;
        const float* wr = w2 + (size_t)j2 * 128;
        float acc = b2[j2];
        for (int d = 0; d < 128; ++d) acc = fmaf(spb[d], wr[d], acc);
        h2[b * 1024 + j2] = acc;
    }
}

// ---------------- AdaWin + LReLU: in [b][C][L] -> out bf16 transposed [b][PDIM][C] ----------------
// R12 winner: sq in 52 registers (static idx), bf16 means, xs [16][352];
// LDS 39.2KB -> 4 blocks/CU; 3 barriers. HW rcp/rsq. Vectorized loads/stores.
// XOUT: also emit bf16 of the raw input, transposed+padded (fused xcvt).
template<bool XOUT, typename TIN>
__global__ __launch_bounds__(256) void adawin_t_kernel(const TIN* __restrict__ in,
        const float* __restrict__ h, const int* __restrict__ lengths,
        __hip_bfloat16* __restrict__ out, __hip_bfloat16* __restrict__ xout, int C) {
    __shared__ float xs[16][352];            // raw x; j=0 <-> l0-48
    __shared__ __hip_bfloat16 msb[16][294];  // means (bf16), mj=0 <-> l0-18
    __shared__ __hip_bfloat16 os[256][16];   // output staging (transposed)
    int l0 = blockIdx.x * 256, c0 = blockIdx.y * 16, b = blockIdx.z;
    int tid = threadIdx.x;
    int c = tid >> 4, sub = tid & 15;
    int len = lengths[b];

    if constexpr (sizeof(TIN) == 4) {       // f32 input: 88 float4 per row
        for (int i = 0; i < 6; ++i) {
            int idx = tid + i * 256;
            if (idx < 16 * 88) {
                int r = idx / 88, j4 = idx % 88;
                int l = l0 - 48 + j4 * 4;
                f32x4 v = {};
                if (l >= 0 && l < LDIM)
                    v = *(const f32x4*)((const float*)in + ((size_t)b * C + c0 + r) * LDIM + l);
                *(f32x4*)&xs[r][j4 * 4] = v;
            }
        }
    } else {                                // bf16 input: 44 short8 per row
        for (int i = 0; i < 3; ++i) {
            int idx = tid + i * 256;
            if (idx < 16 * 44) {
                int r = idx / 44, j8 = idx % 44;
                int l = l0 - 48 + j8 * 8;
                float f[8] = {};
                if (l >= 0 && l < LDIM) {
                    short8 v = *(const short8*)((const __hip_bfloat16*)in +
                                                ((size_t)b * C + c0 + r) * LDIM + l);
                    #pragma unroll
                    for (int k = 0; k < 8; ++k) f[k] = bf2f((unsigned short)v[k]);
                }
                #pragma unroll
                for (int k = 0; k < 8; ++k) xs[r][j8 * 8 + k] = f[k];
            }
        }
    }
    __syncthreads();

    if constexpr (XOUT) {     // fused x -> bf16 transposed (xs is read-only now)
        for (int idx = tid; idx < 512; idx += 256) {
            int row = idx >> 1, hh = idx & 1;
            short8 v;
            #pragma unroll
            for (int k = 0; k < 8; ++k) {
                __hip_bfloat16 t = __float2bfloat16(xs[hh * 8 + k][row + 48]);
                v[k] = *(short*)&t;
            }
            *(short8*)&xout[((size_t)b * PDIM + l0 + row + 1) * 256 + c0 + hh * 8] = v;
            if (l0 == 0 && row == 1)
                *(short8*)&xout[((size_t)b * PDIM) * 256 + c0 + hh * 8] = v;
            if (l0 == LDIM - 256 && row == 254)
                *(short8*)&xout[((size_t)b * PDIM + LDIM + 1) * 256 + c0 + hh * 8] = v;
        }
    }

    // cooperative means for mj in [0,292): l = l0-18+mj
    // window x-idx range [mj+12, mj+48]; numerator unmasked, denom masked
    int mstart = sub * 19;
    int mend = min(mstart + 19, 292);
    float S = 0.f;
    for (int k = 0; k <= 36; ++k) S += xs[c][mstart + k + 12];
    for (int mj = mstart; mj < mend; ++mj) {
        if (mj > mstart) S += xs[c][mj + 48] - xs[c][mj + 11];
        int l = l0 - 18 + mj;
        int lo = max(l - 18, 0), hi = min(l + 19, len);
        float mval = (l >= 0 && l < len)
                   ? S * __builtin_amdgcn_rcpf((float)(hi - lo)) : 0.f;
        msb[c][mj] = __float2bfloat16(mval);
    }
    __syncthreads();

    // register-local: sq[52] covers j in [p-18, p+33], p = l0 + sub*16
    float gamma = h[(size_t)b * 2 * C + c0 + c];
    float beta  = h[(size_t)b * 2 * C + C + c0 + c];
    int lbase = l0 + sub * 16;
    float sq[52], dwn[16];
    #pragma unroll
    for (int k = 0; k < 52; ++k) {
        int j = lbase - 18 + k;
        float d = xs[c][sub * 16 + k + 30] - __bfloat162float(msb[c][sub * 16 + k]);
        if (k >= 18 && k < 34) dwn[k - 18] = d;
        sq[k] = (j >= 0 && j < len) ? d * d : 0.f;
    }
    float S2 = 0.f;
    #pragma unroll
    for (int k = 0; k <= 36; ++k) S2 += sq[k];
    #pragma unroll
    for (int t = 0; t < 16; ++t) {
        int l = lbase + t;
        if (t) S2 += sq[t + 36] - sq[t - 1];
        int lo = max(l - 18, 0), hi = min(l + 19, len);
        float var = (l < len) ? S2 * __builtin_amdgcn_rcpf((float)(hi - lo)) : 0.f;
        float xn = dwn[t] * __builtin_amdgcn_rsqf(var + EPSF);
        float v = fmaf(gamma, xn, xn) + beta;
        v = v > 0.f ? v : 0.2f * v;
        os[sub * 16 + t][c] = __float2bfloat16(v);
    }
    __syncthreads();

    for (int idx = tid; idx < 512; idx += 256) {
        int row = idx >> 1, hh = idx & 1;
        short8 v = *(const short8*)&os[row][hh * 8];
        *(short8*)&out[((size_t)b * PDIM + l0 + row + 1) * C + c0 + hh * 8] = v;
        if (l0 == 0 && row == 1)
            *(short8*)&out[((size_t)b * PDIM) * C + c0 + hh * 8] = v;
        if (l0 == LDIM - 256 && row == 254)
            *(short8*)&out[((size_t)b * PDIM + LDIM + 1) * C + c0 + hh * 8] = v;
    }
}

// ---------------- weight prep ----------------
// [O][I][3] f32 -> [O][3][I] bf16
__global__ void wp3_kernel(const float* __restrict__ in, __hip_bfloat16* __restrict__ o,
                           int I, int total) {
    int idx = blockIdx.x * 256 + threadIdx.x;
    if (idx >= total) return;
    int t = idx % 3;
    int rest = idx / 3;
    int i = rest % I;
    int oo = rest / I;
    o[((size_t)oo * 3 + t) * I + i] = __float2bfloat16(in[idx]);
}

__global__ void wcvt_kernel(const float* __restrict__ in, __hip_bfloat16* __restrict__ o, int total) {
    int idx = blockIdx.x * 256 + threadIdx.x;
    if (idx < total) o[idx] = __float2bfloat16(in[idx]);
}

// ---------------- conv1d(k=3, reflect) as MFMA implicit GEMM ----------------
// R11 m97-invariant K-loop (both operands via global_load_lds, zero per-lane
// global loads in the loop) + R13: 32x32x16 MFMA -- half the MFMA issue slots
// (24 vs 48 per chunk/wave) at the faster 32x32 rate; same ds_read count and
// LDS layout. Fragment maps: A row=lane&31, k=8*(lane>>5); B col=lane&31,
// same k split; C/D col=lane&31, row=(r&3)+8*(r>>2)+4*(lane>>5) [HW-verified
// m74/m101]. Slot involution (ks*2+hi)^((row>>1)&3) on both sides, uniform
// bank coverage. BK=32: act [130][64B] + wt [3][128][64B] = 32.9KB/buffer,
// dbuf 65.8KB -> 2 blocks/CU.
template<int CIN, bool SC, bool FINAL, typename TOUT>
__global__ __launch_bounds__(256, 2) void conv_mfma_kernel(
    const __hip_bfloat16* __restrict__ act,
    const __hip_bfloat16* __restrict__ wt,
    const float* __restrict__ bias,
    const __hip_bfloat16* __restrict__ xsc,
    const __hip_bfloat16* __restrict__ wsc,
    TOUT* __restrict__ out)
{
    constexpr int NCM = CIN / 32;                 // main K-chunks (32 ch each)
    constexpr int NCT = NCM + (SC ? 8 : 0);       // + shortcut chunks
    constexpr int ACT_SZ = 130 * 64;              // 8320
    constexpr int WT_SZ  = 3 * 128 * 64;          // 24576
    constexpr int BUFSZ  = ACT_SZ + WT_SZ;        // 32896
    __shared__ alignas(16) char lds[2][BUFSZ];
    int tid = threadIdx.x;
    int lane = tid & 63;
    int w = tid >> 6, wm = w >> 1, wn = w & 1;    // 2x2 wave grid, 64x64 per wave
    int l0 = blockIdx.x * 128, o0 = blockIdx.y * 128, b = blockIdx.z;
    int il32 = lane & 31, hi = lane >> 5;

    f32x16 acc[2][2] = {};

    auto stage = [&](int kc, char* buf) {
        bool isSC = SC && (kc >= NCM);
        const __hip_bfloat16* asrc;
        int cs, cb;
        if (!isSC) { asrc = act + (size_t)b * PDIM * CIN; cs = CIN; cb = kc * 32; }
        else       { asrc = xsc + (size_t)b * PDIM * 256; cs = 256; cb = (kc - NCM) * 32; }
        // act tile: rows l0-1..l0+128, 64B/row = 4 slots; slot u holds channel
        // group u ^ ((row>>1)&3)  (involution matched by the read)
        for (int u = tid; u < 520; u += 256) {
            int row = u >> 2, s = u & 3;
            int gs = s ^ ((row >> 1) & 3);
            gload_lds16(asrc + (size_t)(l0 + row) * cs + cb + gs * 8,
                        buf + (size_t)(u - lane) * 16);
        }
        // weight tile: [t][row 0..127][4 slots], same per-row involution
        int nwt = isSC ? 512 : 1536;              // SC: 1 tap only
        for (int u = tid; u < nwt; u += 256) {
            int t = u >> 9;
            int rw = (u >> 2) & 127;
            int s = u & 3;
            int gs = s ^ ((rw >> 1) & 3);
            const __hip_bfloat16* wsrc;
            if (!isSC) wsrc = wt + ((size_t)(o0 + rw) * 3 + t) * CIN + kc * 32 + gs * 8;
            else       wsrc = wsc + (size_t)(o0 + rw) * 256 + (kc - NCM) * 32 + gs * 8;
            gload_lds16(wsrc, buf + ACT_SZ + (size_t)(u - lane) * 16);
        }
    };

    stage(0, lds[0]);
    __syncthreads();

    for (int kc = 0; kc < NCT; ++kc) {
        char* cur = lds[kc & 1];
        if (kc + 1 < NCT) stage(kc + 1, lds[(kc + 1) & 1]);

        bool isSC = SC && (kc >= NCM);
        int t0 = isSC ? 1 : 0;        // SC: center tap only (act row shift +1)
        int t1 = isSC ? 2 : 3;
        for (int t = t0; t < t1; ++t) {
            int wtap = isSC ? 0 : t;  // SC weights staged at tap slot 0
            #pragma unroll
            for (int ks = 0; ks < 2; ++ks) {
                short8 af[2], bfr[2];
                #pragma unroll
                for (int mm = 0; mm < 2; ++mm) {
                    int row = wm * 64 + mm * 32 + il32;
                    int s = (ks * 2 + hi) ^ ((row >> 1) & 3);
                    af[mm] = *(const short8*)(cur + ACT_SZ + (wtap * 128 + row) * 64 + s * 16);
                }
                #pragma unroll
                for (int nn = 0; nn < 2; ++nn) {
                    int row = wn * 64 + nn * 32 + il32 + t;    // tap shift = LDS row shift
                    int s = (ks * 2 + hi) ^ ((row >> 1) & 3);
                    bfr[nn] = *(const short8*)(cur + row * 64 + s * 16);
                }
                #pragma unroll
                for (int mm = 0; mm < 2; ++mm)
                    #pragma unroll
                    for (int nn = 0; nn < 2; ++nn)
                        acc[mm][nn] = __builtin_amdgcn_mfma_f32_32x32x16_bf16(
                            af[mm], bfr[nn], acc[mm][nn], 0, 0, 0);
            }
        }
        __syncthreads();
    }

    const float scale = FINAL ? 0.70710678118654752440f : 1.0f;
    #pragma unroll
    for (int mm = 0; mm < 2; ++mm) {
        #pragma unroll
        for (int nn = 0; nn < 2; ++nn) {
            int col = l0 + wn * 64 + nn * 32 + il32;       // C/D: col=lane&31
            #pragma unroll
            for (int r = 0; r < 16; ++r) {
                int row = o0 + wm * 64 + mm * 32 + (r & 3) + 8 * (r >> 2) + 4 * hi;
                float v = (acc[mm][nn][r] + bias[row]) * scale;
                if constexpr (__is_same(TOUT, float))
                    out[((size_t)b * 512 + row) * LDIM + col] = v;
                else
                    out[((size_t)b * 512 + row) * LDIM + col] = __float2bfloat16(v);
            }
        }
    }
}

extern "C" void kernel_launch(void* const* d_in, const int* in_sizes, int n_in,
                              void* d_out, int out_size, void* d_ws, size_t ws_size,
                              hipStream_t stream) {
    const float* x    = (const float*)d_in[0];
    const float* s    = (const float*)d_in[1];
    const int*   lens = (const int*)d_in[2];
    const float* fc1w = (const float*)d_in[3];
    const float* fc1b = (const float*)d_in[4];
    const float* fc2w = (const float*)d_in[5];
    const float* fc2b = (const float*)d_in[6];
    const float* c1w  = (const float*)d_in[7];
    const float* c1b  = (const float*)d_in[8];
    const float* c2w  = (const float*)d_in[9];
    const float* c2b  = (const float*)d_in[10];
    const float* scw  = (const float*)d_in[11];
    float* out = (float*)d_out;

    char* ws = (char*)d_ws;
    float*          sp  = (float*)(ws);
    float*          h1  = (float*)(ws + ((size_t)1 << 20));
    float*          h2  = (float*)(ws + ((size_t)2 << 20));
    __hip_bfloat16* w1t = (__hip_bfloat16*)(ws + ((size_t)3 << 20));   // 512*768*2  = 768KB
    __hip_bfloat16* w2t = (__hip_bfloat16*)(ws + ((size_t)4 << 20));   // 512*1536*2 = 1.5MB
    __hip_bfloat16* wsc = (__hip_bfloat16*)(ws + ((size_t)6 << 20));   // 512*256*2  = 256KB
    __hip_bfloat16* xbf = (__hip_bfloat16*)(ws + ((size_t)8 << 20));   // 16*4098*256*2 = 33.6MB
    __hip_bfloat16* a1t = (__hip_bfloat16*)(ws + ((size_t)42 << 20));  // 33.6MB
    __hip_bfloat16* a2t = (__hip_bfloat16*)(ws + ((size_t)76 << 20));  // 16*4098*512*2 = 67.1MB
    __hip_bfloat16* y1b = (__hip_bfloat16*)d_out;   // bf16 y1 staged in d_out (fully
                                                    // rewritten f32 by final conv2)

    sp_kernel<<<2048, 256, 0, stream>>>(s, lens, sp);
    fc_kernel<<<96, 256, 0, stream>>>(sp, fc1w, fc1b, fc2w, fc2b, h1, h2);
    wp3_kernel<<<(512 * 256 * 3 + 255) / 256, 256, 0, stream>>>(c1w, w1t, 256, 512 * 256 * 3);
    wp3_kernel<<<(512 * 512 * 3 + 255) / 256, 256, 0, stream>>>(c2w, w2t, 512, 512 * 512 * 3);
    wcvt_kernel<<<512, 256, 0, stream>>>(scw, wsc, 512 * 256);

    adawin_t_kernel<true, float><<<dim3(16, 16, 16), 256, 0, stream>>>(
        x, h1, lens, a1t, xbf, 256);
    conv_mfma_kernel<256, false, false, __hip_bfloat16><<<dim3(32, 4, 16), 256, 0, stream>>>(
        a1t, w1t, c1b, nullptr, nullptr, y1b);
    adawin_t_kernel<false, __hip_bfloat16><<<dim3(16, 32, 16), 256, 0, stream>>>(
        y1b, h2, lens, a2t, nullptr, 512);
    conv_mfma_kernel<512, true, true, float><<<dim3(32, 4, 16), 256, 0, stream>>>(
        a2t, w2t, c2b, xbf, wsc, out);
}

// Round 15
// 403.535 us; speedup vs baseline: 1.1004x; 1.1004x over previous
//
#include <hip/hip_runtime.h>
#include <hip/hip_bf16.h>
#include <math.h>

#define LDIM 4096
#define PDIM 4098   // 1-elem reflect pad each side
#define EPSF 1e-9f

using f32x4  = __attribute__((ext_vector_type(4))) float;
using short8 = __attribute__((ext_vector_type(8))) short;

#define AS1 __attribute__((address_space(1)))
#define AS3 __attribute__((address_space(3)))

__device__ __forceinline__ void gload_lds16(const void* g, void* l) {
    __builtin_amdgcn_global_load_lds((const AS1 unsigned int*)g,
                                     (AS3 unsigned int*)l, 16, 0, 0);
}

__device__ __forceinline__ float bf2f(unsigned short u) {
    unsigned int b = ((unsigned int)u) << 16;
    return __builtin_bit_cast(float, b);
}

// ---------------- sp = (s*mask).sum(-1)/len  ----------------
__global__ void sp_kernel(const float* __restrict__ s, const int* __restrict__ lengths,
                          float* __restrict__ sp) {
    int b = blockIdx.x >> 7;
    int d = blockIdx.x & 127;
    int len = lengths[b];
    const float* row = s + ((size_t)(b * 128 + d)) * LDIM;
    float acc = 0.f;
    int len4 = len & ~3;
    for (int l = threadIdx.x * 4; l < len4; l += 1024) {
        f32x4 v = *(const f32x4*)(row + l);
        acc += v[0] + v[1] + v[2] + v[3];
    }
    for (int l = len4 + threadIdx.x; l < len; l += 256) acc += row[l];
    for (int off = 32; off; off >>= 1) acc += __shfl_down(acc, off, 64);
    __shared__ float red[4];
    if ((threadIdx.x & 63) == 0) red[threadIdx.x >> 6] = acc;
    __syncthreads();
    if (threadIdx.x == 0)
        sp[b * 128 + d] = (red[0] + red[1] + red[2] + red[3]) / (float)len;
}

// ---------------- h1 = sp@fc1^T+b1, h2 = sp@fc2^T+b2 ----------------
__global__ void fc_kernel(const float* __restrict__ sp,
                          const float* __restrict__ w1, const float* __restrict__ b1,
                          const float* __restrict__ w2, const float* __restrict__ b2,
                          float* __restrict__ h1, float* __restrict__ h2) {
    int idx = blockIdx.x * 256 + threadIdx.x;   // 16 * 1536
    int b = idx / 1536, j = idx % 1536;
    const float* spb = sp + b * 128;
    if (j < 512) {
        const float* wr = w1 + (size_t)j * 128;
        float acc = b1[j];
        for (int d = 0; d < 128; ++d) acc = fmaf(spb[d], wr[d], acc);
        h1[b * 512 + j] = acc;
    } else {
        int j2 = j - 512;
        const float* wr = w2 + (size_t)j2 * 128;
        float acc = b2[j2];
        for (int d = 0; d < 128; ++d) acc = fmaf(spb[d], wr[d], acc);
        h2[b * 1024 + j2] = acc;
    }
}

// ---------------- AdaWin + LReLU: in [b][C][L] -> out bf16 transposed [b][PDIM][C] ----------------
// R12 winner: sq in 52 registers (static idx), bf16 means, xs [16][352];
// LDS 39.2KB -> 4 blocks/CU; 3 barriers. HW rcp/rsq. Vectorized loads/stores.
// XOUT: also emit bf16 of the raw input, transposed+padded (fused xcvt).
template<bool XOUT, typename TIN>
__global__ __launch_bounds__(256) void adawin_t_kernel(const TIN* __restrict__ in,
        const float* __restrict__ h, const int* __restrict__ lengths,
        __hip_bfloat16* __restrict__ out, __hip_bfloat16* __restrict__ xout, int C) {
    __shared__ float xs[16][352];            // raw x; j=0 <-> l0-48
    __shared__ __hip_bfloat16 msb[16][294];  // means (bf16), mj=0 <-> l0-18
    __shared__ __hip_bfloat16 os[256][16];   // output staging (transposed)
    int l0 = blockIdx.x * 256, c0 = blockIdx.y * 16, b = blockIdx.z;
    int tid = threadIdx.x;
    int c = tid >> 4, sub = tid & 15;
    int len = lengths[b];

    if constexpr (sizeof(TIN) == 4) {       // f32 input: 88 float4 per row
        for (int i = 0; i < 6; ++i) {
            int idx = tid + i * 256;
            if (idx < 16 * 88) {
                int r = idx / 88, j4 = idx % 88;
                int l = l0 - 48 + j4 * 4;
                f32x4 v = {};
                if (l >= 0 && l < LDIM)
                    v = *(const f32x4*)((const float*)in + ((size_t)b * C + c0 + r) * LDIM + l);
                *(f32x4*)&xs[r][j4 * 4] = v;
            }
        }
    } else {                                // bf16 input: 44 short8 per row
        for (int i = 0; i < 3; ++i) {
            int idx = tid + i * 256;
            if (idx < 16 * 44) {
                int r = idx / 44, j8 = idx % 44;
                int l = l0 - 48 + j8 * 8;
                float f[8] = {};
                if (l >= 0 && l < LDIM) {
                    short8 v = *(const short8*)((const __hip_bfloat16*)in +
                                                ((size_t)b * C + c0 + r) * LDIM + l);
                    #pragma unroll
                    for (int k = 0; k < 8; ++k) f[k] = bf2f((unsigned short)v[k]);
                }
                #pragma unroll
                for (int k = 0; k < 8; ++k) xs[r][j8 * 8 + k] = f[k];
            }
        }
    }
    __syncthreads();

    if constexpr (XOUT) {     // fused x -> bf16 transposed (xs is read-only now)
        for (int idx = tid; idx < 512; idx += 256) {
            int row = idx >> 1, hh = idx & 1;
            short8 v;
            #pragma unroll
            for (int k = 0; k < 8; ++k) {
                __hip_bfloat16 t = __float2bfloat16(xs[hh * 8 + k][row + 48]);
                v[k] = *(short*)&t;
            }
            *(short8*)&xout[((size_t)b * PDIM + l0 + row + 1) * 256 + c0 + hh * 8] = v;
            if (l0 == 0 && row == 1)
                *(short8*)&xout[((size_t)b * PDIM) * 256 + c0 + hh * 8] = v;
            if (l0 == LDIM - 256 && row == 254)
                *(short8*)&xout[((size_t)b * PDIM + LDIM + 1) * 256 + c0 + hh * 8] = v;
        }
    }

    // cooperative means for mj in [0,292): l = l0-18+mj
    // window x-idx range [mj+12, mj+48]; numerator unmasked, denom masked
    int mstart = sub * 19;
    int mend = min(mstart + 19, 292);
    float S = 0.f;
    for (int k = 0; k <= 36; ++k) S += xs[c][mstart + k + 12];
    for (int mj = mstart; mj < mend; ++mj) {
        if (mj > mstart) S += xs[c][mj + 48] - xs[c][mj + 11];
        int l = l0 - 18 + mj;
        int lo = max(l - 18, 0), hi = min(l + 19, len);
        float mval = (l >= 0 && l < len)
                   ? S * __builtin_amdgcn_rcpf((float)(hi - lo)) : 0.f;
        msb[c][mj] = __float2bfloat16(mval);
    }
    __syncthreads();

    // register-local: sq[52] covers j in [p-18, p+33], p = l0 + sub*16
    float gamma = h[(size_t)b * 2 * C + c0 + c];
    float beta  = h[(size_t)b * 2 * C + C + c0 + c];
    int lbase = l0 + sub * 16;
    float sq[52], dwn[16];
    #pragma unroll
    for (int k = 0; k < 52; ++k) {
        int j = lbase - 18 + k;
        float d = xs[c][sub * 16 + k + 30] - __bfloat162float(msb[c][sub * 16 + k]);
        if (k >= 18 && k < 34) dwn[k - 18] = d;
        sq[k] = (j >= 0 && j < len) ? d * d : 0.f;
    }
    float S2 = 0.f;
    #pragma unroll
    for (int k = 0; k <= 36; ++k) S2 += sq[k];
    #pragma unroll
    for (int t = 0; t < 16; ++t) {
        int l = lbase + t;
        if (t) S2 += sq[t + 36] - sq[t - 1];
        int lo = max(l - 18, 0), hi = min(l + 19, len);
        float var = (l < len) ? S2 * __builtin_amdgcn_rcpf((float)(hi - lo)) : 0.f;
        float xn = dwn[t] * __builtin_amdgcn_rsqf(var + EPSF);
        float v = fmaf(gamma, xn, xn) + beta;
        v = v > 0.f ? v : 0.2f * v;
        os[sub * 16 + t][c] = __float2bfloat16(v);
    }
    __syncthreads();

    for (int idx = tid; idx < 512; idx += 256) {
        int row = idx >> 1, hh = idx & 1;
        short8 v = *(const short8*)&os[row][hh * 8];
        *(short8*)&out[((size_t)b * PDIM + l0 + row + 1) * C + c0 + hh * 8] = v;
        if (l0 == 0 && row == 1)
            *(short8*)&out[((size_t)b * PDIM) * C + c0 + hh * 8] = v;
        if (l0 == LDIM - 256 && row == 254)
            *(short8*)&out[((size_t)b * PDIM + LDIM + 1) * C + c0 + hh * 8] = v;
    }
}

// ---------------- weight prep ----------------
// [O][I][3] f32 -> [O][3][I] bf16
__global__ void wp3_kernel(const float* __restrict__ in, __hip_bfloat16* __restrict__ o,
                           int I, int total) {
    int idx = blockIdx.x * 256 + threadIdx.x;
    if (idx >= total) return;
    int t = idx % 3;
    int rest = idx / 3;
    int i = rest % I;
    int oo = rest / I;
    o[((size_t)oo * 3 + t) * I + i] = __float2bfloat16(in[idx]);
}

__global__ void wcvt_kernel(const float* __restrict__ in, __hip_bfloat16* __restrict__ o, int total) {
    int idx = blockIdx.x * 256 + threadIdx.x;
    if (idx < total) o[idx] = __float2bfloat16(in[idx]);
}

// ---------------- conv1d(k=3, reflect) as MFMA implicit GEMM ----------------
// R15 = R14 counted-vmcnt pipeline + VMEM ISSUE-ORDER PINS (the R14 NaN):
// counted-vmcnt correctness requires the act group to be the NEWEST vmem ops
// at each wait; the gload_lds builtins are independent memory ops the compiler
// may interleave, so a sched_barrier(0) pins wt-group-before-act-group (and
// act(1)-last in the prologue). These fences cost nothing: staging ops have
// no in-iteration consumers, compute region stays fully schedulable.
//  - act TRIPLE-buffered (3x8.3KB), wt DOUBLE-buffered (2x24.6KB) = 72.4KB.
//  - Wave-uniform stage counts: act = 3 instr/wave (2 full + 1 two-lane halo);
//    wt = 6 (main) / 2 (SC). Steady wait = vmcnt(3): retires act(kc+1)+wt(kc+1),
//    leaves act(kc+2) in flight across the raw s_barrier.
//  - Per-thread staging bases precomputed; in-loop add kc*32.
//  R13 lesson: 32x32 MFMA -> 14.7M bank conflicts with this layout; stay 16x16.
template<int CIN, bool SC, bool FINAL, typename TOUT>
__global__ __launch_bounds__(256, 2) void conv_mfma_kernel(
    const __hip_bfloat16* __restrict__ act,
    const __hip_bfloat16* __restrict__ wt,
    const float* __restrict__ bias,
    const __hip_bfloat16* __restrict__ xsc,
    const __hip_bfloat16* __restrict__ wsc,
    TOUT* __restrict__ out)
{
    constexpr int NCM = CIN / 32;                 // main K-chunks (32 ch each)
    constexpr int NCT = NCM + (SC ? 8 : 0);       // + shortcut chunks
    constexpr int ACT_SZ = 130 * 64;              // 8320
    constexpr int WT_SZ  = 3 * 128 * 64;          // 24576
    constexpr int WT_BASE = 3 * ACT_SZ;           // 24960
    __shared__ alignas(16) char lds[3 * ACT_SZ + 2 * WT_SZ];   // 74112
    int tid = threadIdx.x;
    int lane = tid & 63;
    int w = tid >> 6, wm = w >> 1, wn = w & 1;    // 2x2 wave grid, 64x64 per wave
    int l0 = blockIdx.x * 128, o0 = blockIdx.y * 128, b = blockIdx.z;
    int il = lane & 15, g = lane >> 4;

    f32x4 acc[4][4] = {};

    // ---- precomputed staging descriptors (bases exclude the kc*32 channel adv) ----
    // main act: 512 slots u=tid,tid+256 (rows 1..128) + halo rows 0/129 (2 lanes/wave)
    int u0 = tid, u1 = tid + 256;
    int r0 = 1 + (u0 >> 2), r1 = 1 + (u1 >> 2);
    int gs0 = (u0 & 3) ^ ((r0 >> 1) & 3);
    int gs1 = (u1 & 3) ^ ((r1 >> 1) & 3);
    int hrow = (w < 2) ? 0 : 129;
    int hslot = (w & 1) * 2 + (lane & 1);         // rows 0/129 have XOR term 0
    int dA0 = 64 + (u0 - lane) * 16;
    int dA1 = 64 + (u1 - lane) * 16;
    int dAH = ((w < 2) ? 0 : 8256) + (w & 1) * 32;
    const __hip_bfloat16* mabase = act + (size_t)b * PDIM * CIN;
    const __hip_bfloat16* mA0 = mabase + (size_t)(l0 + r0) * CIN + gs0 * 8;
    const __hip_bfloat16* mA1 = mabase + (size_t)(l0 + r1) * CIN + gs1 * 8;
    const __hip_bfloat16* mAH = mabase + (size_t)(l0 + hrow) * CIN + hslot * 8;
    // main wt: 6 slots u=tid+i*256; layout byte = u*16
    const __hip_bfloat16* mW[6];
    int dW0 = (tid - lane) * 16;
    #pragma unroll
    for (int i = 0; i < 6; ++i) {
        int u = tid + i * 256;
        int t = u >> 9, rw = (u >> 2) & 127;
        int gsw = (u & 3) ^ ((rw >> 1) & 3);
        mW[i] = wt + ((size_t)(o0 + rw) * 3 + t) * CIN + gsw * 8;
    }
    // SC descriptors (conv2 only)
    const __hip_bfloat16 *sA0 = nullptr, *sA1 = nullptr, *sAH = nullptr, *sW0 = nullptr, *sW1 = nullptr;
    if constexpr (SC) {
        const __hip_bfloat16* sabase = xsc + (size_t)b * PDIM * 256;
        sA0 = sabase + (size_t)(l0 + r0) * 256 + gs0 * 8;
        sA1 = sabase + (size_t)(l0 + r1) * 256 + gs1 * 8;
        sAH = sabase + (size_t)(l0 + hrow) * 256 + hslot * 8;
        {
            int ua = tid, ub = tid + 256;
            int rwa = (ua >> 2) & 127, rwb = (ub >> 2) & 127;
            int ga = (ua & 3) ^ ((rwa >> 1) & 3);
            int gb = (ub & 3) ^ ((rwb >> 1) & 3);
            sW0 = wsc + (size_t)(o0 + rwa) * 256 + ga * 8;
            sW1 = wsc + (size_t)(o0 + rwb) * 256 + gb * 8;
        }
    }

    auto stage_act = [&](int kc, int bi) {
        char* buf = lds + bi * ACT_SZ;
        if (!SC || kc < NCM) {
            int cb = kc * 32;
            gload_lds16(mA0 + cb, buf + dA0);
            gload_lds16(mA1 + cb, buf + dA1);
            if ((tid & 63) < 2) gload_lds16(mAH + cb, buf + dAH);
        } else if constexpr (SC) {
            int cb = (kc - NCM) * 32;
            gload_lds16(sA0 + cb, buf + dA0);
            gload_lds16(sA1 + cb, buf + dA1);
            if ((tid & 63) < 2) gload_lds16(sAH + cb, buf + dAH);
        }
    };
    auto stage_wt = [&](int kc, int wbi) {
        char* buf = lds + WT_BASE + wbi * WT_SZ;
        if (!SC || kc < NCM) {
            int cb = kc * 32;
            #pragma unroll
            for (int i = 0; i < 6; ++i)
                gload_lds16(mW[i] + cb, buf + dW0 + i * 4096);
        } else if constexpr (SC) {
            int cb = (kc - NCM) * 32;
            gload_lds16(sW0 + cb, buf + dW0);
            gload_lds16(sW1 + cb, buf + dW0 + 4096);
        }
    };

    // ---- prologue: wt(0), act(0) | act(1) LAST (pin); leave act(1) flying ----
    stage_wt(0, 0);
    stage_act(0, 0);
    __builtin_amdgcn_sched_barrier(0);    // act(1) must be the NEWEST vmem ops
    stage_act(1, 1);
    asm volatile("s_waitcnt vmcnt(3)" ::: "memory");
    __builtin_amdgcn_s_barrier();
    __builtin_amdgcn_sched_barrier(0);

    int ab = 0, wb = 0;
    for (int kc = 0; kc < NCT; ++kc) {
        int ab2 = (ab >= 1) ? ab - 1 : 2;          // (kc+2)%3
        if (kc + 1 < NCT) stage_wt(kc + 1, wb ^ 1);
        __builtin_amdgcn_sched_barrier(0);         // pin: wt group before act group
        if (kc + 2 < NCT) stage_act(kc + 2, ab2);

        const char* abuf = lds + ab * ACT_SZ;
        const char* wbuf = lds + WT_BASE + wb * WT_SZ;
        bool isSC = SC && (kc >= NCM);
        int t0 = isSC ? 1 : 0;        // SC: center tap only (act row shift +1)
        int t1 = isSC ? 2 : 3;
        for (int t = t0; t < t1; ++t) {
            int wtap = isSC ? 0 : t;  // SC weights staged at tap slot 0
            short8 af[4], bfr[4];
            #pragma unroll
            for (int mm = 0; mm < 4; ++mm) {
                int row = wm * 64 + mm * 16 + il;
                int s = g ^ ((row >> 1) & 3);
                af[mm] = *(const short8*)(wbuf + (wtap * 128 + row) * 64 + s * 16);
            }
            #pragma unroll
            for (int nn = 0; nn < 4; ++nn) {
                int row = wn * 64 + nn * 16 + il + t;      // tap shift = LDS row shift
                int s = g ^ ((row >> 1) & 3);
                bfr[nn] = *(const short8*)(abuf + row * 64 + s * 16);
            }
            #pragma unroll
            for (int mm = 0; mm < 4; ++mm)
                #pragma unroll
                for (int nn = 0; nn < 4; ++nn)
                    acc[mm][nn] = __builtin_amdgcn_mfma_f32_16x16x32_bf16(
                        af[mm], bfr[nn], acc[mm][nn], 0, 0, 0);
        }

        if (kc < NCT - 1) {
            if (kc < NCT - 2) asm volatile("s_waitcnt vmcnt(3)" ::: "memory");
            else              asm volatile("s_waitcnt vmcnt(0)" ::: "memory");
            __builtin_amdgcn_s_barrier();
            __builtin_amdgcn_sched_barrier(0);
        }
        ab = (ab == 2) ? 0 : ab + 1;
        wb ^= 1;
    }

    const float scale = FINAL ? 0.70710678118654752440f : 1.0f;
    #pragma unroll
    for (int mm = 0; mm < 4; ++mm) {
        #pragma unroll
        for (int j = 0; j < 4; ++j) {
            int row = o0 + wm * 64 + mm * 16 + g * 4 + j;  // C/D: row=(lane>>4)*4+reg
            float bv = bias[row];
            #pragma unroll
            for (int nn = 0; nn < 4; ++nn) {
                int col = l0 + wn * 64 + nn * 16 + il;     // C/D: col=lane&15
                float v = (acc[mm][nn][j] + bv) * scale;
                if constexpr (__is_same(TOUT, float))
                    out[((size_t)b * 512 + row) * LDIM + col] = v;
                else
                    out[((size_t)b * 512 + row) * LDIM + col] = __float2bfloat16(v);
            }
        }
    }
}

extern "C" void kernel_launch(void* const* d_in, const int* in_sizes, int n_in,
                              void* d_out, int out_size, void* d_ws, size_t ws_size,
                              hipStream_t stream) {
    const float* x    = (const float*)d_in[0];
    const float* s    = (const float*)d_in[1];
    const int*   lens = (const int*)d_in[2];
    const float* fc1w = (const float*)d_in[3];
    const float* fc1b = (const float*)d_in[4];
    const float* fc2w = (const float*)d_in[5];
    const float* fc2b = (const float*)d_in[6];
    const float* c1w  = (const float*)d_in[7];
    const float* c1b  = (const float*)d_in[8];
    const float* c2w  = (const float*)d_in[9];
    const float* c2b  = (const float*)d_in[10];
    const float* scw  = (const float*)d_in[11];
    float* out = (float*)d_out;

    char* ws = (char*)d_ws;
    float*          sp  = (float*)(ws);
    float*          h1  = (float*)(ws + ((size_t)1 << 20));
    float*          h2  = (float*)(ws + ((size_t)2 << 20));
    __hip_bfloat16* w1t = (__hip_bfloat16*)(ws + ((size_t)3 << 20));   // 512*768*2  = 768KB
    __hip_bfloat16* w2t = (__hip_bfloat16*)(ws + ((size_t)4 << 20));   // 512*1536*2 = 1.5MB
    __hip_bfloat16* wsc = (__hip_bfloat16*)(ws + ((size_t)6 << 20));   // 512*256*2  = 256KB
    __hip_bfloat16* xbf = (__hip_bfloat16*)(ws + ((size_t)8 << 20));   // 16*4098*256*2 = 33.6MB
    __hip_bfloat16* a1t = (__hip_bfloat16*)(ws + ((size_t)42 << 20));  // 33.6MB
    __hip_bfloat16* a2t = (__hip_bfloat16*)(ws + ((size_t)76 << 20));  // 16*4098*512*2 = 67.1MB
    __hip_bfloat16* y1b = (__hip_bfloat16*)d_out;   // bf16 y1 staged in d_out (fully
                                                    // rewritten f32 by final conv2)

    sp_kernel<<<2048, 256, 0, stream>>>(s, lens, sp);
    fc_kernel<<<96, 256, 0, stream>>>(sp, fc1w, fc1b, fc2w, fc2b, h1, h2);
    wp3_kernel<<<(512 * 256 * 3 + 255) / 256, 256, 0, stream>>>(c1w, w1t, 256, 512 * 256 * 3);
    wp3_kernel<<<(512 * 512 * 3 + 255) / 256, 256, 0, stream>>>(c2w, w2t, 512, 512 * 512 * 3);
    wcvt_kernel<<<512, 256, 0, stream>>>(scw, wsc, 512 * 256);

    adawin_t_kernel<true, float><<<dim3(16, 16, 16), 256, 0, stream>>>(
        x, h1, lens, a1t, xbf, 256);
    conv_mfma_kernel<256, false, false, __hip_bfloat16><<<dim3(32, 4, 16), 256, 0, stream>>>(
        a1t, w1t, c1b, nullptr, nullptr, y1b);
    adawin_t_kernel<false, __hip_bfloat16><<<dim3(16, 32, 16), 256, 0, stream>>>(
        y1b, h2, lens, a2t, nullptr, 512);
    conv_mfma_kernel<512, true, true, float><<<dim3(32, 4, 16), 256, 0, stream>>>(
        a2t, w2t, c2b, xbf, wsc, out);
}

// Round 16
// 342.983 us; speedup vs baseline: 1.2947x; 1.1765x over previous
//
#include <hip/hip_runtime.h>
#include <hip/hip_bf16.h>
#include <math.h>

#define LDIM 4096
#define PDIM 4098   // 1-elem reflect pad each side
#define EPSF 1e-9f

using f32x4  = __attribute__((ext_vector_type(4))) float;
using short8 = __attribute__((ext_vector_type(8))) short;

#define AS1 __attribute__((address_space(1)))
#define AS3 __attribute__((address_space(3)))

__device__ __forceinline__ void gload_lds16(const void* g, void* l) {
    __builtin_amdgcn_global_load_lds((const AS1 unsigned int*)g,
                                     (AS3 unsigned int*)l, 16, 0, 0);
}

__device__ __forceinline__ float bf2f(unsigned short u) {
    unsigned int b = ((unsigned int)u) << 16;
    return __builtin_bit_cast(float, b);
}

// ---------------- sp = (s*mask).sum(-1)/len  ----------------
__global__ void sp_kernel(const float* __restrict__ s, const int* __restrict__ lengths,
                          float* __restrict__ sp) {
    int b = blockIdx.x >> 7;
    int d = blockIdx.x & 127;
    int len = lengths[b];
    const float* row = s + ((size_t)(b * 128 + d)) * LDIM;
    float acc = 0.f;
    int len4 = len & ~3;
    for (int l = threadIdx.x * 4; l < len4; l += 1024) {
        f32x4 v = *(const f32x4*)(row + l);
        acc += v[0] + v[1] + v[2] + v[3];
    }
    for (int l = len4 + threadIdx.x; l < len; l += 256) acc += row[l];
    for (int off = 32; off; off >>= 1) acc += __shfl_down(acc, off, 64);
    __shared__ float red[4];
    if ((threadIdx.x & 63) == 0) red[threadIdx.x >> 6] = acc;
    __syncthreads();
    if (threadIdx.x == 0)
        sp[b * 128 + d] = (red[0] + red[1] + red[2] + red[3]) / (float)len;
}

// ---------------- h1 = sp@fc1^T+b1, h2 = sp@fc2^T+b2 ----------------
__global__ void fc_kernel(const float* __restrict__ sp,
                          const float* __restrict__ w1, const float* __restrict__ b1,
                          const float* __restrict__ w2, const float* __restrict__ b2,
                          float* __restrict__ h1, float* __restrict__ h2) {
    int idx = blockIdx.x * 256 + threadIdx.x;   // 16 * 1536
    int b = idx / 1536, j = idx % 1536;
    const float* spb = sp + b * 128;
    if (j < 512) {
        const float* wr = w1 + (size_t)j * 128;
        float acc = b1[j];
        for (int d = 0; d < 128; ++d) acc = fmaf(spb[d], wr[d], acc);
        h1[b * 512 + j] = acc;
    } else {
        int j2 = j - 512;
        const float* wr = w2 + (size_t)j2 * 128;
        float acc = b2[j2];
        for (int d = 0; d < 128; ++d) acc = fmaf(spb[d], wr[d], acc);
        h2[b * 1024 + j2] = acc;
    }
}

// ---------------- AdaWin + LReLU: in [b][C][L] -> out bf16 transposed [b][PDIM][C] ----------------
// R16 bank-conflict fix (math bit-identical to R12):
//  - role swap c=tid&15, sub=tid>>4 (was c=tid>>4): a wave's scalar xs reads
//    previously hit banks {K,K+16} only (row stride 352 ≡ 0 mod 32 banks +
//    sub*16 stride) = 32-WAY conflict on ~140 reads/thread; os 2B writes also
//    32-way.
//  - xs row 352 -> 356 floats (stride ≡ 4 mod 32, rows stay 16B-aligned):
//    reads now (4c + 16sub + K) mod 32 = 16 banks -> 4-way (1.58x, m136);
//    os writes 8-way; msb ~2-way (147-bank odd stride).
// XOUT: also emit bf16 of the raw input, transposed+padded (fused xcvt).
template<bool XOUT, typename TIN>
__global__ __launch_bounds__(256) void adawin_t_kernel(const TIN* __restrict__ in,
        const float* __restrict__ h, const int* __restrict__ lengths,
        __hip_bfloat16* __restrict__ out, __hip_bfloat16* __restrict__ xout, int C) {
    __shared__ float xs[16][356];            // raw x; j=0 <-> l0-48 (4-float row pad)
    __shared__ __hip_bfloat16 msb[16][294];  // means (bf16), mj=0 <-> l0-18
    __shared__ __hip_bfloat16 os[256][16];   // output staging (transposed)
    int l0 = blockIdx.x * 256, c0 = blockIdx.y * 16, b = blockIdx.z;
    int tid = threadIdx.x;
    int c = tid & 15, sub = tid >> 4;        // R16 role swap (was c=tid>>4, sub=tid&15)
    int len = lengths[b];

    if constexpr (sizeof(TIN) == 4) {       // f32 input: 88 float4 per row
        for (int i = 0; i < 6; ++i) {
            int idx = tid + i * 256;
            if (idx < 16 * 88) {
                int r = idx / 88, j4 = idx % 88;
                int l = l0 - 48 + j4 * 4;
                f32x4 v = {};
                if (l >= 0 && l < LDIM)
                    v = *(const f32x4*)((const float*)in + ((size_t)b * C + c0 + r) * LDIM + l);
                *(f32x4*)&xs[r][j4 * 4] = v;
            }
        }
    } else {                                // bf16 input: 44 short8 per row
        for (int i = 0; i < 3; ++i) {
            int idx = tid + i * 256;
            if (idx < 16 * 44) {
                int r = idx / 44, j8 = idx % 44;
                int l = l0 - 48 + j8 * 8;
                float f[8] = {};
                if (l >= 0 && l < LDIM) {
                    short8 v = *(const short8*)((const __hip_bfloat16*)in +
                                                ((size_t)b * C + c0 + r) * LDIM + l);
                    #pragma unroll
                    for (int k = 0; k < 8; ++k) f[k] = bf2f((unsigned short)v[k]);
                }
                #pragma unroll
                for (int k = 0; k < 8; ++k) xs[r][j8 * 8 + k] = f[k];
            }
        }
    }
    __syncthreads();

    if constexpr (XOUT) {     // fused x -> bf16 transposed (xs is read-only now)
        for (int idx = tid; idx < 512; idx += 256) {
            int row = idx >> 1, hh = idx & 1;
            short8 v;
            #pragma unroll
            for (int k = 0; k < 8; ++k) {
                __hip_bfloat16 t = __float2bfloat16(xs[hh * 8 + k][row + 48]);
                v[k] = *(short*)&t;
            }
            *(short8*)&xout[((size_t)b * PDIM + l0 + row + 1) * 256 + c0 + hh * 8] = v;
            if (l0 == 0 && row == 1)
                *(short8*)&xout[((size_t)b * PDIM) * 256 + c0 + hh * 8] = v;
            if (l0 == LDIM - 256 && row == 254)
                *(short8*)&xout[((size_t)b * PDIM + LDIM + 1) * 256 + c0 + hh * 8] = v;
        }
    }

    // cooperative means for mj in [0,292): l = l0-18+mj
    // window x-idx range [mj+12, mj+48]; numerator unmasked, denom masked
    int mstart = sub * 19;
    int mend = min(mstart + 19, 292);
    float S = 0.f;
    for (int k = 0; k <= 36; ++k) S += xs[c][mstart + k + 12];
    for (int mj = mstart; mj < mend; ++mj) {
        if (mj > mstart) S += xs[c][mj + 48] - xs[c][mj + 11];
        int l = l0 - 18 + mj;
        int lo = max(l - 18, 0), hi = min(l + 19, len);
        float mval = (l >= 0 && l < len)
                   ? S * __builtin_amdgcn_rcpf((float)(hi - lo)) : 0.f;
        msb[c][mj] = __float2bfloat16(mval);
    }
    __syncthreads();

    // register-local: sq[52] covers j in [p-18, p+33], p = l0 + sub*16
    float gamma = h[(size_t)b * 2 * C + c0 + c];
    float beta  = h[(size_t)b * 2 * C + C + c0 + c];
    int lbase = l0 + sub * 16;
    float sq[52], dwn[16];
    #pragma unroll
    for (int k = 0; k < 52; ++k) {
        int j = lbase - 18 + k;
        float d = xs[c][sub * 16 + k + 30] - __bfloat162float(msb[c][sub * 16 + k]);
        if (k >= 18 && k < 34) dwn[k - 18] = d;
        sq[k] = (j >= 0 && j < len) ? d * d : 0.f;
    }
    float S2 = 0.f;
    #pragma unroll
    for (int k = 0; k <= 36; ++k) S2 += sq[k];
    #pragma unroll
    for (int t = 0; t < 16; ++t) {
        int l = lbase + t;
        if (t) S2 += sq[t + 36] - sq[t - 1];
        int lo = max(l - 18, 0), hi = min(l + 19, len);
        float var = (l < len) ? S2 * __builtin_amdgcn_rcpf((float)(hi - lo)) : 0.f;
        float xn = dwn[t] * __builtin_amdgcn_rsqf(var + EPSF);
        float v = fmaf(gamma, xn, xn) + beta;
        v = v > 0.f ? v : 0.2f * v;
        os[sub * 16 + t][c] = __float2bfloat16(v);
    }
    __syncthreads();

    for (int idx = tid; idx < 512; idx += 256) {
        int row = idx >> 1, hh = idx & 1;
        short8 v = *(const short8*)&os[row][hh * 8];
        *(short8*)&out[((size_t)b * PDIM + l0 + row + 1) * C + c0 + hh * 8] = v;
        if (l0 == 0 && row == 1)
            *(short8*)&out[((size_t)b * PDIM) * C + c0 + hh * 8] = v;
        if (l0 == LDIM - 256 && row == 254)
            *(short8*)&out[((size_t)b * PDIM + LDIM + 1) * C + c0 + hh * 8] = v;
    }
}

// ---------------- weight prep ----------------
// [O][I][3] f32 -> [O][3][I] bf16
__global__ void wp3_kernel(const float* __restrict__ in, __hip_bfloat16* __restrict__ o,
                           int I, int total) {
    int idx = blockIdx.x * 256 + threadIdx.x;
    if (idx >= total) return;
    int t = idx % 3;
    int rest = idx / 3;
    int i = rest % I;
    int oo = rest / I;
    o[((size_t)oo * 3 + t) * I + i] = __float2bfloat16(in[idx]);
}

__global__ void wcvt_kernel(const float* __restrict__ in, __hip_bfloat16* __restrict__ o, int total) {
    int idx = blockIdx.x * 256 + threadIdx.x;
    if (idx < total) o[idx] = __float2bfloat16(in[idx]);
}

// ---------------- conv1d(k=3, reflect) as MFMA implicit GEMM ----------------
// R15 WINNER (conv2 145us, MfmaUtil 37%, 0 conflicts): counted-vmcnt pipeline
// with vmem issue-order pins. m97-invariant K-loop: both operands staged via
// global_load_lds, zero per-lane global loads in the loop.
//  - act TRIPLE-buffered (3x8.3KB), wt DOUBLE-buffered (2x24.6KB) = 72.4KB.
//  - Wave-uniform stage counts: act = 3 instr/wave (2 full + 1 two-lane halo);
//    wt = 6 (main) / 2 (SC). Steady wait = vmcnt(3): retires act(kc+1)+wt(kc+1),
//    leaves act(kc+2) in flight across the raw s_barrier.
//  - sched_barrier(0) pins wt-group-before-act-group (R14 NaN: compiler may
//    interleave independent gload_lds ops; act must be NEWEST at the wait).
//  - Per-thread staging bases precomputed; in-loop add kc*32.
//  R13 lesson: 32x32 MFMA -> 14.7M bank conflicts with this layout; stay 16x16.
template<int CIN, bool SC, bool FINAL, typename TOUT>
__global__ __launch_bounds__(256, 2) void conv_mfma_kernel(
    const __hip_bfloat16* __restrict__ act,
    const __hip_bfloat16* __restrict__ wt,
    const float* __restrict__ bias,
    const __hip_bfloat16* __restrict__ xsc,
    const __hip_bfloat16* __restrict__ wsc,
    TOUT* __restrict__ out)
{
    constexpr int NCM = CIN / 32;                 // main K-chunks (32 ch each)
    constexpr int NCT = NCM + (SC ? 8 : 0);       // + shortcut chunks
    constexpr int ACT_SZ = 130 * 64;              // 8320
    constexpr int WT_SZ  = 3 * 128 * 64;          // 24576
    constexpr int WT_BASE = 3 * ACT_SZ;           // 24960
    __shared__ alignas(16) char lds[3 * ACT_SZ + 2 * WT_SZ];   // 74112
    int tid = threadIdx.x;
    int lane = tid & 63;
    int w = tid >> 6, wm = w >> 1, wn = w & 1;    // 2x2 wave grid, 64x64 per wave
    int l0 = blockIdx.x * 128, o0 = blockIdx.y * 128, b = blockIdx.z;
    int il = lane & 15, g = lane >> 4;

    f32x4 acc[4][4] = {};

    // ---- precomputed staging descriptors (bases exclude the kc*32 channel adv) ----
    // main act: 512 slots u=tid,tid+256 (rows 1..128) + halo rows 0/129 (2 lanes/wave)
    int u0 = tid, u1 = tid + 256;
    int r0 = 1 + (u0 >> 2), r1 = 1 + (u1 >> 2);
    int gs0 = (u0 & 3) ^ ((r0 >> 1) & 3);
    int gs1 = (u1 & 3) ^ ((r1 >> 1) & 3);
    int hrow = (w < 2) ? 0 : 129;
    int hslot = (w & 1) * 2 + (lane & 1);         // rows 0/129 have XOR term 0
    int dA0 = 64 + (u0 - lane) * 16;
    int dA1 = 64 + (u1 - lane) * 16;
    int dAH = ((w < 2) ? 0 : 8256) + (w & 1) * 32;
    const __hip_bfloat16* mabase = act + (size_t)b * PDIM * CIN;
    const __hip_bfloat16* mA0 = mabase + (size_t)(l0 + r0) * CIN + gs0 * 8;
    const __hip_bfloat16* mA1 = mabase + (size_t)(l0 + r1) * CIN + gs1 * 8;
    const __hip_bfloat16* mAH = mabase + (size_t)(l0 + hrow) * CIN + hslot * 8;
    // main wt: 6 slots u=tid+i*256; layout byte = u*16
    const __hip_bfloat16* mW[6];
    int dW0 = (tid - lane) * 16;
    #pragma unroll
    for (int i = 0; i < 6; ++i) {
        int u = tid + i * 256;
        int t = u >> 9, rw = (u >> 2) & 127;
        int gsw = (u & 3) ^ ((rw >> 1) & 3);
        mW[i] = wt + ((size_t)(o0 + rw) * 3 + t) * CIN + gsw * 8;
    }
    // SC descriptors (conv2 only)
    const __hip_bfloat16 *sA0 = nullptr, *sA1 = nullptr, *sAH = nullptr, *sW0 = nullptr, *sW1 = nullptr;
    if constexpr (SC) {
        const __hip_bfloat16* sabase = xsc + (size_t)b * PDIM * 256;
        sA0 = sabase + (size_t)(l0 + r0) * 256 + gs0 * 8;
        sA1 = sabase + (size_t)(l0 + r1) * 256 + gs1 * 8;
        sAH = sabase + (size_t)(l0 + hrow) * 256 + hslot * 8;
        {
            int ua = tid, ub = tid + 256;
            int rwa = (ua >> 2) & 127, rwb = (ub >> 2) & 127;
            int ga = (ua & 3) ^ ((rwa >> 1) & 3);
            int gb = (ub & 3) ^ ((rwb >> 1) & 3);
            sW0 = wsc + (size_t)(o0 + rwa) * 256 + ga * 8;
            sW1 = wsc + (size_t)(o0 + rwb) * 256 + gb * 8;
        }
    }

    auto stage_act = [&](int kc, int bi) {
        char* buf = lds + bi * ACT_SZ;
        if (!SC || kc < NCM) {
            int cb = kc * 32;
            gload_lds16(mA0 + cb, buf + dA0);
            gload_lds16(mA1 + cb, buf + dA1);
            if ((tid & 63) < 2) gload_lds16(mAH + cb, buf + dAH);
        } else if constexpr (SC) {
            int cb = (kc - NCM) * 32;
            gload_lds16(sA0 + cb, buf + dA0);
            gload_lds16(sA1 + cb, buf + dA1);
            if ((tid & 63) < 2) gload_lds16(sAH + cb, buf + dAH);
        }
    };
    auto stage_wt = [&](int kc, int wbi) {
        char* buf = lds + WT_BASE + wbi * WT_SZ;
        if (!SC || kc < NCM) {
            int cb = kc * 32;
            #pragma unroll
            for (int i = 0; i < 6; ++i)
                gload_lds16(mW[i] + cb, buf + dW0 + i * 4096);
        } else if constexpr (SC) {
            int cb = (kc - NCM) * 32;
            gload_lds16(sW0 + cb, buf + dW0);
            gload_lds16(sW1 + cb, buf + dW0 + 4096);
        }
    };

    // ---- prologue: wt(0), act(0) | act(1) LAST (pin); leave act(1) flying ----
    stage_wt(0, 0);
    stage_act(0, 0);
    __builtin_amdgcn_sched_barrier(0);    // act(1) must be the NEWEST vmem ops
    stage_act(1, 1);
    asm volatile("s_waitcnt vmcnt(3)" ::: "memory");
    __builtin_amdgcn_s_barrier();
    __builtin_amdgcn_sched_barrier(0);

    int ab = 0, wb = 0;
    for (int kc = 0; kc < NCT; ++kc) {
        int ab2 = (ab >= 1) ? ab - 1 : 2;          // (kc+2)%3
        if (kc + 1 < NCT) stage_wt(kc + 1, wb ^ 1);
        __builtin_amdgcn_sched_barrier(0);         // pin: wt group before act group
        if (kc + 2 < NCT) stage_act(kc + 2, ab2);

        const char* abuf = lds + ab * ACT_SZ;
        const char* wbuf = lds + WT_BASE + wb * WT_SZ;
        bool isSC = SC && (kc >= NCM);
        int t0 = isSC ? 1 : 0;        // SC: center tap only (act row shift +1)
        int t1 = isSC ? 2 : 3;
        for (int t = t0; t < t1; ++t) {
            int wtap = isSC ? 0 : t;  // SC weights staged at tap slot 0
            short8 af[4], bfr[4];
            #pragma unroll
            for (int mm = 0; mm < 4; ++mm) {
                int row = wm * 64 + mm * 16 + il;
                int s = g ^ ((row >> 1) & 3);
                af[mm] = *(const short8*)(wbuf + (wtap * 128 + row) * 64 + s * 16);
            }
            #pragma unroll
            for (int nn = 0; nn < 4; ++nn) {
                int row = wn * 64 + nn * 16 + il + t;      // tap shift = LDS row shift
                int s = g ^ ((row >> 1) & 3);
                bfr[nn] = *(const short8*)(abuf + row * 64 + s * 16);
            }
            #pragma unroll
            for (int mm = 0; mm < 4; ++mm)
                #pragma unroll
                for (int nn = 0; nn < 4; ++nn)
                    acc[mm][nn] = __builtin_amdgcn_mfma_f32_16x16x32_bf16(
                        af[mm], bfr[nn], acc[mm][nn], 0, 0, 0);
        }

        if (kc < NCT - 1) {
            if (kc < NCT - 2) asm volatile("s_waitcnt vmcnt(3)" ::: "memory");
            else              asm volatile("s_waitcnt vmcnt(0)" ::: "memory");
            __builtin_amdgcn_s_barrier();
            __builtin_amdgcn_sched_barrier(0);
        }
        ab = (ab == 2) ? 0 : ab + 1;
        wb ^= 1;
    }

    const float scale = FINAL ? 0.70710678118654752440f : 1.0f;
    #pragma unroll
    for (int mm = 0; mm < 4; ++mm) {
        #pragma unroll
        for (int j = 0; j < 4; ++j) {
            int row = o0 + wm * 64 + mm * 16 + g * 4 + j;  // C/D: row=(lane>>4)*4+reg
            float bv = bias[row];
            #pragma unroll
            for (int nn = 0; nn < 4; ++nn) {
                int col = l0 + wn * 64 + nn * 16 + il;     // C/D: col=lane&15
                float v = (acc[mm][nn][j] + bv) * scale;
                if constexpr (__is_same(TOUT, float))
                    out[((size_t)b * 512 + row) * LDIM + col] = v;
                else
                    out[((size_t)b * 512 + row) * LDIM + col] = __float2bfloat16(v);
            }
        }
    }
}

extern "C" void kernel_launch(void* const* d_in, const int* in_sizes, int n_in,
                              void* d_out, int out_size, void* d_ws, size_t ws_size,
                              hipStream_t stream) {
    const float* x    = (const float*)d_in[0];
    const float* s    = (const float*)d_in[1];
    const int*   lens = (const int*)d_in[2];
    const float* fc1w = (const float*)d_in[3];
    const float* fc1b = (const float*)d_in[4];
    const float* fc2w = (const float*)d_in[5];
    const float* fc2b = (const float*)d_in[6];
    const float* c1w  = (const float*)d_in[7];
    const float* c1b  = (const float*)d_in[8];
    const float* c2w  = (const float*)d_in[9];
    const float* c2b  = (const float*)d_in[10];
    const float* scw  = (const float*)d_in[11];
    float* out = (float*)d_out;

    char* ws = (char*)d_ws;
    float*          sp  = (float*)(ws);
    float*          h1  = (float*)(ws + ((size_t)1 << 20));
    float*          h2  = (float*)(ws + ((size_t)2 << 20));
    __hip_bfloat16* w1t = (__hip_bfloat16*)(ws + ((size_t)3 << 20));   // 512*768*2  = 768KB
    __hip_bfloat16* w2t = (__hip_bfloat16*)(ws + ((size_t)4 << 20));   // 512*1536*2 = 1.5MB
    __hip_bfloat16* wsc = (__hip_bfloat16*)(ws + ((size_t)6 << 20));   // 512*256*2  = 256KB
    __hip_bfloat16* xbf = (__hip_bfloat16*)(ws + ((size_t)8 << 20));   // 16*4098*256*2 = 33.6MB
    __hip_bfloat16* a1t = (__hip_bfloat16*)(ws + ((size_t)42 << 20));  // 33.6MB
    __hip_bfloat16* a2t = (__hip_bfloat16*)(ws + ((size_t)76 << 20));  // 16*4098*512*2 = 67.1MB
    __hip_bfloat16* y1b = (__hip_bfloat16*)d_out;   // bf16 y1 staged in d_out (fully
                                                    // rewritten f32 by final conv2)

    sp_kernel<<<2048, 256, 0, stream>>>(s, lens, sp);
    fc_kernel<<<96, 256, 0, stream>>>(sp, fc1w, fc1b, fc2w, fc2b, h1, h2);
    wp3_kernel<<<(512 * 256 * 3 + 255) / 256, 256, 0, stream>>>(c1w, w1t, 256, 512 * 256 * 3);
    wp3_kernel<<<(512 * 512 * 3 + 255) / 256, 256, 0, stream>>>(c2w, w2t, 512, 512 * 512 * 3);
    wcvt_kernel<<<512, 256, 0, stream>>>(scw, wsc, 512 * 256);

    adawin_t_kernel<true, float><<<dim3(16, 16, 16), 256, 0, stream>>>(
        x, h1, lens, a1t, xbf, 256);
    conv_mfma_kernel<256, false, false, __hip_bfloat16><<<dim3(32, 4, 16), 256, 0, stream>>>(
        a1t, w1t, c1b, nullptr, nullptr, y1b);
    adawin_t_kernel<false, __hip_bfloat16><<<dim3(16, 32, 16), 256, 0, stream>>>(
        y1b, h2, lens, a2t, nullptr, 512);
    conv_mfma_kernel<512, true, true, float><<<dim3(32, 4, 16), 256, 0, stream>>>(
        a2t, w2t, c2b, xbf, wsc, out);
}

// Round 17
// 332.953 us; speedup vs baseline: 1.3337x; 1.0301x over previous
//
#include <hip/hip_runtime.h>
#include <hip/hip_bf16.h>
#include <math.h>

#define LDIM 4096
#define PDIM 4098   // 1-elem reflect pad each side
#define EPSF 1e-9f

using f32x4  = __attribute__((ext_vector_type(4))) float;
using short8 = __attribute__((ext_vector_type(8))) short;

#define AS1 __attribute__((address_space(1)))
#define AS3 __attribute__((address_space(3)))

__device__ __forceinline__ void gload_lds16(const void* g, void* l) {
    __builtin_amdgcn_global_load_lds((const AS1 unsigned int*)g,
                                     (AS3 unsigned int*)l, 16, 0, 0);
}

__device__ __forceinline__ float bf2f(unsigned short u) {
    unsigned int b = ((unsigned int)u) << 16;
    return __builtin_bit_cast(float, b);
}

// ---------------- sp = (s*mask).sum(-1)/len  ----------------
__global__ void sp_kernel(const float* __restrict__ s, const int* __restrict__ lengths,
                          float* __restrict__ sp) {
    int b = blockIdx.x >> 7;
    int d = blockIdx.x & 127;
    int len = lengths[b];
    const float* row = s + ((size_t)(b * 128 + d)) * LDIM;
    float acc = 0.f;
    int len4 = len & ~3;
    for (int l = threadIdx.x * 4; l < len4; l += 1024) {
        f32x4 v = *(const f32x4*)(row + l);
        acc += v[0] + v[1] + v[2] + v[3];
    }
    for (int l = len4 + threadIdx.x; l < len; l += 256) acc += row[l];
    for (int off = 32; off; off >>= 1) acc += __shfl_down(acc, off, 64);
    __shared__ float red[4];
    if ((threadIdx.x & 63) == 0) red[threadIdx.x >> 6] = acc;
    __syncthreads();
    if (threadIdx.x == 0)
        sp[b * 128 + d] = (red[0] + red[1] + red[2] + red[3]) / (float)len;
}

// ---------------- h1 = sp@fc1^T+b1, h2 = sp@fc2^T+b2 ----------------
__global__ void fc_kernel(const float* __restrict__ sp,
                          const float* __restrict__ w1, const float* __restrict__ b1,
                          const float* __restrict__ w2, const float* __restrict__ b2,
                          float* __restrict__ h1, float* __restrict__ h2) {
    int idx = blockIdx.x * 256 + threadIdx.x;   // 16 * 1536
    int b = idx / 1536, j = idx % 1536;
    const float* spb = sp + b * 128;
    if (j < 512) {
        const float* wr = w1 + (size_t)j * 128;
        float acc = b1[j];
        for (int d = 0; d < 128; ++d) acc = fmaf(spb[d], wr[d], acc);
        h1[b * 512 + j] = acc;
    } else {
        int j2 = j - 512;
        const float* wr = w2 + (size_t)j2 * 128;
        float acc = b2[j2];
        for (int d = 0; d < 128; ++d) acc = fmaf(spb[d], wr[d], acc);
        h2[b * 1024 + j2] = acc;
    }
}

// ---------------- AdaWin + LReLU: in [b][C][L] -> out bf16 transposed [b][PDIM][C] ----------------
// R17: REGISTER-RESIDENT means. Each thread owns outputs [lbase, lbase+16) and
// needs x over [lbase-36, lbase+51] = 88 floats, 16B-aligned in xs at
// [c][sub*16+12..+99] -> 22 x ds_read_b128 (xq[22]). Means computed in the
// same rolling pass as sq/dwn (f32, no bf16 quantization). Deletes: the
// cooperative means loop (~73 scalar ds_read), msb array (9.4KB LDS) + its
// 52-read readback, and one barrier. Per-thread LDS ops ~125 scalar -> 22 b128.
// VGPR ~185 -> __launch_bounds__(256,2). R16 role map (c=tid&15) + 356-pad kept.
// XOUT: also emit bf16 of the raw input, transposed+padded (fused xcvt).
template<bool XOUT, typename TIN>
__global__ __launch_bounds__(256, 2) void adawin_t_kernel(const TIN* __restrict__ in,
        const float* __restrict__ h, const int* __restrict__ lengths,
        __hip_bfloat16* __restrict__ out, __hip_bfloat16* __restrict__ xout, int C) {
    __shared__ float xs[16][356];            // raw x; j=0 <-> l0-48 (4-float row pad)
    __shared__ __hip_bfloat16 os[256][16];   // output staging (transposed)
    int l0 = blockIdx.x * 256, c0 = blockIdx.y * 16, b = blockIdx.z;
    int tid = threadIdx.x;
    int c = tid & 15, sub = tid >> 4;
    int len = lengths[b];

    if constexpr (sizeof(TIN) == 4) {       // f32 input: 88 float4 per row
        for (int i = 0; i < 6; ++i) {
            int idx = tid + i * 256;
            if (idx < 16 * 88) {
                int r = idx / 88, j4 = idx % 88;
                int l = l0 - 48 + j4 * 4;
                f32x4 v = {};
                if (l >= 0 && l < LDIM)
                    v = *(const f32x4*)((const float*)in + ((size_t)b * C + c0 + r) * LDIM + l);
                *(f32x4*)&xs[r][j4 * 4] = v;
            }
        }
    } else {                                // bf16 input: 44 short8 per row
        for (int i = 0; i < 3; ++i) {
            int idx = tid + i * 256;
            if (idx < 16 * 44) {
                int r = idx / 44, j8 = idx % 44;
                int l = l0 - 48 + j8 * 8;
                float f[8] = {};
                if (l >= 0 && l < LDIM) {
                    short8 v = *(const short8*)((const __hip_bfloat16*)in +
                                                ((size_t)b * C + c0 + r) * LDIM + l);
                    #pragma unroll
                    for (int k = 0; k < 8; ++k) f[k] = bf2f((unsigned short)v[k]);
                }
                #pragma unroll
                for (int k = 0; k < 8; ++k) xs[r][j8 * 8 + k] = f[k];
            }
        }
    }
    __syncthreads();

    if constexpr (XOUT) {     // fused x -> bf16 transposed (xs is read-only)
        for (int idx = tid; idx < 512; idx += 256) {
            int row = idx >> 1, hh = idx & 1;
            short8 v;
            #pragma unroll
            for (int k = 0; k < 8; ++k) {
                __hip_bfloat16 t = __float2bfloat16(xs[hh * 8 + k][row + 48]);
                v[k] = *(short*)&t;
            }
            *(short8*)&xout[((size_t)b * PDIM + l0 + row + 1) * 256 + c0 + hh * 8] = v;
            if (l0 == 0 && row == 1)
                *(short8*)&xout[((size_t)b * PDIM) * 256 + c0 + hh * 8] = v;
            if (l0 == LDIM - 256 && row == 254)
                *(short8*)&xout[((size_t)b * PDIM + LDIM + 1) * 256 + c0 + hh * 8] = v;
        }
    }

    // own x span -> registers: xv[m] = x[lbase-36+m], m in [0,88)
    f32x4 xq[22];
    #pragma unroll
    for (int i = 0; i < 22; ++i)
        xq[i] = *(const f32x4*)&xs[c][sub * 16 + 12 + 4 * i];
    #define XV(m) (xq[(m) >> 2][(m) & 3])

    float gamma = h[(size_t)b * 2 * C + c0 + c];
    float beta  = h[(size_t)b * 2 * C + C + c0 + c];
    int lbase = l0 + sub * 16;

    // fused rolling pass: mean[j] (f32), d, sq, dwn for j = lbase-18+k, k=0..51
    float S = 0.f;
    #pragma unroll
    for (int m = 0; m <= 36; ++m) S += XV(m);
    float sq[52], dwn[16];
    #pragma unroll
    for (int k = 0; k < 52; ++k) {
        if (k) S += XV(k + 36) - XV(k - 1);
        int j = lbase - 18 + k;
        int lo = max(j - 18, 0), hi = min(j + 19, len);
        float mean = (j >= 0 && j < len)
                   ? S * __builtin_amdgcn_rcpf((float)(hi - lo)) : 0.f;
        float d = XV(k + 18) - mean;
        if (k >= 18 && k < 34) dwn[k - 18] = d;
        sq[k] = (j >= 0 && j < len) ? d * d : 0.f;
    }
    #undef XV

    float S2 = 0.f;
    #pragma unroll
    for (int k = 0; k <= 36; ++k) S2 += sq[k];
    #pragma unroll
    for (int t = 0; t < 16; ++t) {
        int l = lbase + t;
        if (t) S2 += sq[t + 36] - sq[t - 1];
        int lo = max(l - 18, 0), hi = min(l + 19, len);
        float var = (l < len) ? S2 * __builtin_amdgcn_rcpf((float)(hi - lo)) : 0.f;
        float xn = dwn[t] * __builtin_amdgcn_rsqf(var + EPSF);
        float v = fmaf(gamma, xn, xn) + beta;
        v = v > 0.f ? v : 0.2f * v;
        os[sub * 16 + t][c] = __float2bfloat16(v);
    }
    __syncthreads();

    for (int idx = tid; idx < 512; idx += 256) {
        int row = idx >> 1, hh = idx & 1;
        short8 v = *(const short8*)&os[row][hh * 8];
        *(short8*)&out[((size_t)b * PDIM + l0 + row + 1) * C + c0 + hh * 8] = v;
        if (l0 == 0 && row == 1)
            *(short8*)&out[((size_t)b * PDIM) * C + c0 + hh * 8] = v;
        if (l0 == LDIM - 256 && row == 254)
            *(short8*)&out[((size_t)b * PDIM + LDIM + 1) * C + c0 + hh * 8] = v;
    }
}

// ---------------- weight prep ----------------
// [O][I][3] f32 -> [O][3][I] bf16
__global__ void wp3_kernel(const float* __restrict__ in, __hip_bfloat16* __restrict__ o,
                           int I, int total) {
    int idx = blockIdx.x * 256 + threadIdx.x;
    if (idx >= total) return;
    int t = idx % 3;
    int rest = idx / 3;
    int i = rest % I;
    int oo = rest / I;
    o[((size_t)oo * 3 + t) * I + i] = __float2bfloat16(in[idx]);
}

__global__ void wcvt_kernel(const float* __restrict__ in, __hip_bfloat16* __restrict__ o, int total) {
    int idx = blockIdx.x * 256 + threadIdx.x;
    if (idx < total) o[idx] = __float2bfloat16(in[idx]);
}

// ---------------- conv1d(k=3, reflect) as MFMA implicit GEMM ----------------
// R15 WINNER (conv2 145us, MfmaUtil 37%, 0 conflicts): counted-vmcnt pipeline
// with vmem issue-order pins. m97-invariant K-loop: both operands staged via
// global_load_lds, zero per-lane global loads in the loop.
//  - act TRIPLE-buffered (3x8.3KB), wt DOUBLE-buffered (2x24.6KB) = 72.4KB.
//  - Wave-uniform stage counts: act = 3 instr/wave (2 full + 1 two-lane halo);
//    wt = 6 (main) / 2 (SC). Steady wait = vmcnt(3): retires act(kc+1)+wt(kc+1),
//    leaves act(kc+2) in flight across the raw s_barrier.
//  - sched_barrier(0) pins wt-group-before-act-group (R14 NaN: compiler may
//    interleave independent gload_lds ops; act must be NEWEST at the wait).
//  - Per-thread staging bases precomputed; in-loop add kc*32.
//  R13 lesson: 32x32 MFMA -> 14.7M bank conflicts with this layout; stay 16x16.
template<int CIN, bool SC, bool FINAL, typename TOUT>
__global__ __launch_bounds__(256, 2) void conv_mfma_kernel(
    const __hip_bfloat16* __restrict__ act,
    const __hip_bfloat16* __restrict__ wt,
    const float* __restrict__ bias,
    const __hip_bfloat16* __restrict__ xsc,
    const __hip_bfloat16* __restrict__ wsc,
    TOUT* __restrict__ out)
{
    constexpr int NCM = CIN / 32;                 // main K-chunks (32 ch each)
    constexpr int NCT = NCM + (SC ? 8 : 0);       // + shortcut chunks
    constexpr int ACT_SZ = 130 * 64;              // 8320
    constexpr int WT_SZ  = 3 * 128 * 64;          // 24576
    constexpr int WT_BASE = 3 * ACT_SZ;           // 24960
    __shared__ alignas(16) char lds[3 * ACT_SZ + 2 * WT_SZ];   // 74112
    int tid = threadIdx.x;
    int lane = tid & 63;
    int w = tid >> 6, wm = w >> 1, wn = w & 1;    // 2x2 wave grid, 64x64 per wave
    int l0 = blockIdx.x * 128, o0 = blockIdx.y * 128, b = blockIdx.z;
    int il = lane & 15, g = lane >> 4;

    f32x4 acc[4][4] = {};

    // ---- precomputed staging descriptors (bases exclude the kc*32 channel adv) ----
    // main act: 512 slots u=tid,tid+256 (rows 1..128) + halo rows 0/129 (2 lanes/wave)
    int u0 = tid, u1 = tid + 256;
    int r0 = 1 + (u0 >> 2), r1 = 1 + (u1 >> 2);
    int gs0 = (u0 & 3) ^ ((r0 >> 1) & 3);
    int gs1 = (u1 & 3) ^ ((r1 >> 1) & 3);
    int hrow = (w < 2) ? 0 : 129;
    int hslot = (w & 1) * 2 + (lane & 1);         // rows 0/129 have XOR term 0
    int dA0 = 64 + (u0 - lane) * 16;
    int dA1 = 64 + (u1 - lane) * 16;
    int dAH = ((w < 2) ? 0 : 8256) + (w & 1) * 32;
    const __hip_bfloat16* mabase = act + (size_t)b * PDIM * CIN;
    const __hip_bfloat16* mA0 = mabase + (size_t)(l0 + r0) * CIN + gs0 * 8;
    const __hip_bfloat16* mA1 = mabase + (size_t)(l0 + r1) * CIN + gs1 * 8;
    const __hip_bfloat16* mAH = mabase + (size_t)(l0 + hrow) * CIN + hslot * 8;
    // main wt: 6 slots u=tid+i*256; layout byte = u*16
    const __hip_bfloat16* mW[6];
    int dW0 = (tid - lane) * 16;
    #pragma unroll
    for (int i = 0; i < 6; ++i) {
        int u = tid + i * 256;
        int t = u >> 9, rw = (u >> 2) & 127;
        int gsw = (u & 3) ^ ((rw >> 1) & 3);
        mW[i] = wt + ((size_t)(o0 + rw) * 3 + t) * CIN + gsw * 8;
    }
    // SC descriptors (conv2 only)
    const __hip_bfloat16 *sA0 = nullptr, *sA1 = nullptr, *sAH = nullptr, *sW0 = nullptr, *sW1 = nullptr;
    if constexpr (SC) {
        const __hip_bfloat16* sabase = xsc + (size_t)b * PDIM * 256;
        sA0 = sabase + (size_t)(l0 + r0) * 256 + gs0 * 8;
        sA1 = sabase + (size_t)(l0 + r1) * 256 + gs1 * 8;
        sAH = sabase + (size_t)(l0 + hrow) * 256 + hslot * 8;
        {
            int ua = tid, ub = tid + 256;
            int rwa = (ua >> 2) & 127, rwb = (ub >> 2) & 127;
            int ga = (ua & 3) ^ ((rwa >> 1) & 3);
            int gb = (ub & 3) ^ ((rwb >> 1) & 3);
            sW0 = wsc + (size_t)(o0 + rwa) * 256 + ga * 8;
            sW1 = wsc + (size_t)(o0 + rwb) * 256 + gb * 8;
        }
    }

    auto stage_act = [&](int kc, int bi) {
        char* buf = lds + bi * ACT_SZ;
        if (!SC || kc < NCM) {
            int cb = kc * 32;
            gload_lds16(mA0 + cb, buf + dA0);
            gload_lds16(mA1 + cb, buf + dA1);
            if ((tid & 63) < 2) gload_lds16(mAH + cb, buf + dAH);
        } else if constexpr (SC) {
            int cb = (kc - NCM) * 32;
            gload_lds16(sA0 + cb, buf + dA0);
            gload_lds16(sA1 + cb, buf + dA1);
            if ((tid & 63) < 2) gload_lds16(sAH + cb, buf + dAH);
        }
    };
    auto stage_wt = [&](int kc, int wbi) {
        char* buf = lds + WT_BASE + wbi * WT_SZ;
        if (!SC || kc < NCM) {
            int cb = kc * 32;
            #pragma unroll
            for (int i = 0; i < 6; ++i)
                gload_lds16(mW[i] + cb, buf + dW0 + i * 4096);
        } else if constexpr (SC) {
            int cb = (kc - NCM) * 32;
            gload_lds16(sW0 + cb, buf + dW0);
            gload_lds16(sW1 + cb, buf + dW0 + 4096);
        }
    };

    // ---- prologue: wt(0), act(0) | act(1) LAST (pin); leave act(1) flying ----
    stage_wt(0, 0);
    stage_act(0, 0);
    __builtin_amdgcn_sched_barrier(0);    // act(1) must be the NEWEST vmem ops
    stage_act(1, 1);
    asm volatile("s_waitcnt vmcnt(3)" ::: "memory");
    __builtin_amdgcn_s_barrier();
    __builtin_amdgcn_sched_barrier(0);

    int ab = 0, wb = 0;
    for (int kc = 0; kc < NCT; ++kc) {
        int ab2 = (ab >= 1) ? ab - 1 : 2;          // (kc+2)%3
        if (kc + 1 < NCT) stage_wt(kc + 1, wb ^ 1);
        __builtin_amdgcn_sched_barrier(0);         // pin: wt group before act group
        if (kc + 2 < NCT) stage_act(kc + 2, ab2);

        const char* abuf = lds + ab * ACT_SZ;
        const char* wbuf = lds + WT_BASE + wb * WT_SZ;
        bool isSC = SC && (kc >= NCM);
        int t0 = isSC ? 1 : 0;        // SC: center tap only (act row shift +1)
        int t1 = isSC ? 2 : 3;
        for (int t = t0; t < t1; ++t) {
            int wtap = isSC ? 0 : t;  // SC weights staged at tap slot 0
            short8 af[4], bfr[4];
            #pragma unroll
            for (int mm = 0; mm < 4; ++mm) {
                int row = wm * 64 + mm * 16 + il;
                int s = g ^ ((row >> 1) & 3);
                af[mm] = *(const short8*)(wbuf + (wtap * 128 + row) * 64 + s * 16);
            }
            #pragma unroll
            for (int nn = 0; nn < 4; ++nn) {
                int row = wn * 64 + nn * 16 + il + t;      // tap shift = LDS row shift
                int s = g ^ ((row >> 1) & 3);
                bfr[nn] = *(const short8*)(abuf + row * 64 + s * 16);
            }
            #pragma unroll
            for (int mm = 0; mm < 4; ++mm)
                #pragma unroll
                for (int nn = 0; nn < 4; ++nn)
                    acc[mm][nn] = __builtin_amdgcn_mfma_f32_16x16x32_bf16(
                        af[mm], bfr[nn], acc[mm][nn], 0, 0, 0);
        }

        if (kc < NCT - 1) {
            if (kc < NCT - 2) asm volatile("s_waitcnt vmcnt(3)" ::: "memory");
            else              asm volatile("s_waitcnt vmcnt(0)" ::: "memory");
            __builtin_amdgcn_s_barrier();
            __builtin_amdgcn_sched_barrier(0);
        }
        ab = (ab == 2) ? 0 : ab + 1;
        wb ^= 1;
    }

    const float scale = FINAL ? 0.70710678118654752440f : 1.0f;
    #pragma unroll
    for (int mm = 0; mm < 4; ++mm) {
        #pragma unroll
        for (int j = 0; j < 4; ++j) {
            int row = o0 + wm * 64 + mm * 16 + g * 4 + j;  // C/D: row=(lane>>4)*4+reg
            float bv = bias[row];
            #pragma unroll
            for (int nn = 0; nn < 4; ++nn) {
                int col = l0 + wn * 64 + nn * 16 + il;     // C/D: col=lane&15
                float v = (acc[mm][nn][j] + bv) * scale;
                if constexpr (__is_same(TOUT, float))
                    out[((size_t)b * 512 + row) * LDIM + col] = v;
                else
                    out[((size_t)b * 512 + row) * LDIM + col] = __float2bfloat16(v);
            }
        }
    }
}

extern "C" void kernel_launch(void* const* d_in, const int* in_sizes, int n_in,
                              void* d_out, int out_size, void* d_ws, size_t ws_size,
                              hipStream_t stream) {
    const float* x    = (const float*)d_in[0];
    const float* s    = (const float*)d_in[1];
    const int*   lens = (const int*)d_in[2];
    const float* fc1w = (const float*)d_in[3];
    const float* fc1b = (const float*)d_in[4];
    const float* fc2w = (const float*)d_in[5];
    const float* fc2b = (const float*)d_in[6];
    const float* c1w  = (const float*)d_in[7];
    const float* c1b  = (const float*)d_in[8];
    const float* c2w  = (const float*)d_in[9];
    const float* c2b  = (const float*)d_in[10];
    const float* scw  = (const float*)d_in[11];
    float* out = (float*)d_out;

    char* ws = (char*)d_ws;
    float*          sp  = (float*)(ws);
    float*          h1  = (float*)(ws + ((size_t)1 << 20));
    float*          h2  = (float*)(ws + ((size_t)2 << 20));
    __hip_bfloat16* w1t = (__hip_bfloat16*)(ws + ((size_t)3 << 20));   // 512*768*2  = 768KB
    __hip_bfloat16* w2t = (__hip_bfloat16*)(ws + ((size_t)4 << 20));   // 512*1536*2 = 1.5MB
    __hip_bfloat16* wsc = (__hip_bfloat16*)(ws + ((size_t)6 << 20));   // 512*256*2  = 256KB
    __hip_bfloat16* xbf = (__hip_bfloat16*)(ws + ((size_t)8 << 20));   // 16*4098*256*2 = 33.6MB
    __hip_bfloat16* a1t = (__hip_bfloat16*)(ws + ((size_t)42 << 20));  // 33.6MB
    __hip_bfloat16* a2t = (__hip_bfloat16*)(ws + ((size_t)76 << 20));  // 16*4098*512*2 = 67.1MB
    __hip_bfloat16* y1b = (__hip_bfloat16*)d_out;   // bf16 y1 staged in d_out (fully
                                                    // rewritten f32 by final conv2)

    sp_kernel<<<2048, 256, 0, stream>>>(s, lens, sp);
    fc_kernel<<<96, 256, 0, stream>>>(sp, fc1w, fc1b, fc2w, fc2b, h1, h2);
    wp3_kernel<<<(512 * 256 * 3 + 255) / 256, 256, 0, stream>>>(c1w, w1t, 256, 512 * 256 * 3);
    wp3_kernel<<<(512 * 512 * 3 + 255) / 256, 256, 0, stream>>>(c2w, w2t, 512, 512 * 512 * 3);
    wcvt_kernel<<<512, 256, 0, stream>>>(scw, wsc, 512 * 256);

    adawin_t_kernel<true, float><<<dim3(16, 16, 16), 256, 0, stream>>>(
        x, h1, lens, a1t, xbf, 256);
    conv_mfma_kernel<256, false, false, __hip_bfloat16><<<dim3(32, 4, 16), 256, 0, stream>>>(
        a1t, w1t, c1b, nullptr, nullptr, y1b);
    adawin_t_kernel<false, __hip_bfloat16><<<dim3(16, 32, 16), 256, 0, stream>>>(
        y1b, h2, lens, a2t, nullptr, 512);
    conv_mfma_kernel<512, true, true, float><<<dim3(32, 4, 16), 256, 0, stream>>>(
        a2t, w2t, c2b, xbf, wsc, out);
}